// Round 1
// baseline (637.207 us; speedup 1.0000x reference)
//
#include <hip/hip_runtime.h>
#include <hip/hip_fp16.h>

#define NN 50000
#define NE 800000
#define D 128
#define NB 196        // ceil(50000/256)
#define TOT_BLOCKS 4152   // 1024 fill (interleaved) + 3128 gemm
#define RNG 6250      // NN / 8 (dst range per XCD)
#define ESL 6250      // NE / 128 (edge slice per fill-rank)

typedef _Float16 half8_t __attribute__((ext_vector_type(8)));
typedef _Float16 half4_t __attribute__((ext_vector_type(4)));
typedef float f32x4 __attribute__((ext_vector_type(4)));

// ---------------- K0: init counters + summary slots ----------------
__global__ void k_init(int* cnt1, int* cnt2, float* s1, float* s2) {
    int i = blockIdx.x * blockDim.x + threadIdx.x;
    int stride = gridDim.x * blockDim.x;
    for (int j = i; j < NN; j += stride) { cnt1[j] = 0; cnt2[j] = 0; }
    if (i < D) { s1[i] = 0.f; s2[i] = 0.f; }
}

// ---------------- K1: in-degree histogram, XCD-binned ----------------
__global__ void k_count(const int* __restrict__ dst1, const int* __restrict__ dst2,
                        int* cnt1, int* cnt2) {
    int r = blockIdx.x & 7;
    int rank = blockIdx.x >> 3;          // 0..127
    unsigned lo = r * RNG;
    int base = rank * ESL;
    for (int e = base + threadIdx.x; e < base + ESL; e += 256) {
        int d1 = dst1[e];
        if ((unsigned)(d1 - lo) < RNG) atomicAdd(&cnt1[d1], 1);
        int d2 = dst2[e];
        if ((unsigned)(d2 - lo) < RNG) atomicAdd(&cnt2[d2], 1);
    }
}

// ---------------- K2a: per-block partial sums of counts (both graphs) ----------------
__global__ void k_part(const int* __restrict__ cnt1, const int* __restrict__ cnt2,
                       int* part1, int* part2) {
    __shared__ int sm1[256], sm2[256];
    int t = threadIdx.x;
    int idx = blockIdx.x * 256 + t;
    int v1 = (idx < NN) ? cnt1[idx] : 0;
    int v2 = (idx < NN) ? cnt2[idx] : 0;
    sm1[t] = v1; sm2[t] = v2;
    __syncthreads();
    for (int off = 128; off > 0; off >>= 1) {
        if (t < off) { sm1[t] += sm1[t + off]; sm2[t] += sm2[t + off]; }
        __syncthreads();
    }
    if (t == 0) { part1[blockIdx.x] = sm1[0]; part2[blockIdx.x] = sm2[0]; }
}

// ---------------- K2b: exclusive scan of block partials (one block) ----------------
__global__ void k_scanp(int* part1, int* part2) {
    __shared__ int sm1[256], sm2[256];
    int t = threadIdx.x;
    int v1 = (t < NB) ? part1[t] : 0;
    int v2 = (t < NB) ? part2[t] : 0;
    sm1[t] = v1; sm2[t] = v2;
    __syncthreads();
    for (int off = 1; off < 256; off <<= 1) {
        int a1 = (t >= off) ? sm1[t - off] : 0;
        int a2 = (t >= off) ? sm2[t - off] : 0;
        __syncthreads();
        sm1[t] += a1; sm2[t] += a2;
        __syncthreads();
    }
    if (t < NB) { part1[t] = sm1[t] - v1; part2[t] = sm2[t] - v2; }
}

// ---------------- K2c: apply block offsets -> rp, cur, dinv ----------------
__global__ void k_apply(const int* __restrict__ cnt1, const int* __restrict__ cnt2,
                        const int* __restrict__ part1, const int* __restrict__ part2,
                        int* rp1, int* rp2, int* cur1, int* cur2,
                        float* dinv1, float* dinv2) {
    __shared__ int sm1[256], sm2[256];
    int b = blockIdx.x, t = threadIdx.x;
    int idx = b * 256 + t;
    int v1 = (idx < NN) ? cnt1[idx] : 0;
    int v2 = (idx < NN) ? cnt2[idx] : 0;
    sm1[t] = v1; sm2[t] = v2;
    __syncthreads();
    for (int off = 1; off < 256; off <<= 1) {
        int a1 = (t >= off) ? sm1[t - off] : 0;
        int a2 = (t >= off) ? sm2[t - off] : 0;
        __syncthreads();
        sm1[t] += a1; sm2[t] += a2;
        __syncthreads();
    }
    int e1 = sm1[t] - v1 + part1[b];  // exclusive prefix
    int e2 = sm2[t] - v2 + part2[b];
    if (idx < NN) {
        rp1[idx] = e1; cur1[idx] = e1; dinv1[idx] = rsqrtf((float)(v1 + 1));
        rp2[idx] = e2; cur2[idx] = e2; dinv2[idx] = rsqrtf((float)(v2 + 1));
    } else if (idx == NN) {
        rp1[NN] = e1; rp2[NN] = e2;
    }
}

// ---------------- K3+K4 merged: interleaved XCD-binned CSR fill + 4 GEMMs ----------------
// Fill blocks are INTERLEAVED through the dispatch ((g&3)==0 of each 8-block group, g<512)
// so fill (atomic-latency-bound) overlaps GEMM (load/MFMA-bound) instead of running as a
// solo phase that owns all 1024 resident block slots first.
// GEMM: swapped MFMA operands (W=A, x=B) -> lane holds 4 consecutive out-cols of ONE row;
// epilogue transposes via the (now dead) WT LDS so every global store instruction writes
// 16 full aligned 64B lines.
__launch_bounds__(256)
__global__ void k_fill_gemm(const int* __restrict__ src1, const int* __restrict__ dst1,
                            const int* __restrict__ src2, const int* __restrict__ dst2,
                            int* cur1, int* cur2, int* col1, int* col2,
                            const float* __restrict__ x,
                            const float* __restrict__ W1, const float* __restrict__ W2,
                            const float* __restrict__ mp1, const float* __restrict__ mn1,
                            const float* __restrict__ mp2, const float* __restrict__ mn2,
                            const int* __restrict__ perm1, const int* __restrict__ perm2,
                            const float* __restrict__ dinv1, const float* __restrict__ dinv2,
                            _Float16* xwi1, _Float16* xwi2) {
    __shared__ __align__(16) _Float16 WT[128][136];   // 34816 B -> 4 blocks/CU
    int t = threadIdx.x;
    int bid = blockIdx.x;
    int grp = bid >> 3;

    if (((grp & 3) == 0) && (grp < 512)) {
        // ---- FILL block: rank 0..127, r = bid&7 preserved (XCD-local atomics) ----
        int r = bid & 7;
        int rank = grp >> 2;              // 0..127
        unsigned lo = r * RNG;
        int base = rank * ESL;
        for (int e = base + t; e < base + ESL; e += 256) {
            int d1 = dst1[e];
            if ((unsigned)(d1 - lo) < RNG) {
                int p = atomicAdd(&cur1[d1], 1);
                col1[p] = src1[e];
            }
            int d2 = dst2[e];
            if ((unsigned)(d2 - lo) < RNG) {
                int p = atomicAdd(&cur2[d2], 1);
                col2[p] = src2[e];
            }
        }
        return;
    }

    // ---- GEMM block ----
    int g = bid - 8 * min((grp + 3) >> 2, 128);   // 0..3127
    int which = g / 782;                   // 0 = pos1, 1 = neg1, 2 = pos2, 3 = neg2
    int bx = g - which * 782;
    const float* W = (which < 2) ? W1 : W2;
    const float* mask = (which == 0) ? mp1 : (which == 1) ? mn1 : (which == 2) ? mp2 : mn2;
    const int* perm = (which == 1) ? perm1 : (which == 3) ? perm2 : nullptr;
    const float* dinv = (which < 2) ? dinv1 : dinv2;
    _Float16* out = ((which < 2) ? xwi1 : xwi2) + ((which & 1) ? 128 : 0);

    // W staging: column-chunk loads (4B coalesced, 256B/row-instr) + half8 16B LDS writes.
    // b128 write: 8 lanes/bank over 8 min phases -> conflict-free (vs old 16-32-way
    // scalar-write conflicts = the measured 2.56e7 SQ_LDS_BANK_CONFLICT).
    #pragma unroll
    for (int i = 0; i < 8; i++) {
        int idx = i * 256 + t;            // 0..2047
        int j = idx & 127;
        int k0 = (idx >> 7) * 8;          // 0,8,...,120
        half8_t h;
        #pragma unroll
        for (int c = 0; c < 8; c++) h[c] = (_Float16)W[(k0 + c) * 128 + j];
        *(half8_t*)(&WT[j][k0]) = h;      // WT[n][k], fp16
    }
    __syncthreads();

    int wave = t >> 6;
    int lane = t & 63;
    int quad = lane >> 4;
    int m = lane & 15;
    int tile = bx * 4 + wave;
    bool active = (tile * 16 < NN);       // tiles 0..3124 active; NO early return (barriers below)

    f32x4 accs[8];
    if (active) {
        int row = tile * 16 + m;
        int grow = perm ? perm[row] : row;
        const float* xrow = x + (long)grow * D;
        const float* mrow = mask + (long)grow * D;

        half8_t a[4];
        #pragma unroll
        for (int kk = 0; kk < 4; kk++) {
            int k0 = kk * 32 + quad * 8;
            float4 xa = *(const float4*)(xrow + k0);
            float4 xb = *(const float4*)(xrow + k0 + 4);
            float4 ma = *(const float4*)(mrow + k0);
            float4 mb = *(const float4*)(mrow + k0 + 4);
            a[kk][0] = (_Float16)(xa.x * ma.x);
            a[kk][1] = (_Float16)(xa.y * ma.y);
            a[kk][2] = (_Float16)(xa.z * ma.z);
            a[kk][3] = (_Float16)(xa.w * ma.w);
            a[kk][4] = (_Float16)(xb.x * mb.x);
            a[kk][5] = (_Float16)(xb.y * mb.y);
            a[kk][6] = (_Float16)(xb.z * mb.z);
            a[kk][7] = (_Float16)(xb.w * mb.w);
        }

        // Swapped operands: A = W-fragment (i = out-col), B = x-fragment (j = x-row).
        // Lane (quad,m): D rows = out-cols nt*16+quad*4+reg, D col = x-row tile*16+m.
        #pragma unroll
        for (int nt = 0; nt < 8; nt++) {
            f32x4 acc = {0.f, 0.f, 0.f, 0.f};
            #pragma unroll
            for (int kk = 0; kk < 4; kk++) {
                half8_t w = *(const half8_t*)(&WT[nt * 16 + m][kk * 32 + quad * 8]);
                acc = __builtin_amdgcn_mfma_f32_16x16x32_f16(w, a[kk], acc, 0, 0, 0);
            }
            accs[nt] = acc;
        }
    }

    // All waves done reading WT -> reuse it as per-wave transpose staging.
    __syncthreads();

    if (active) {
        float ds = dinv[tile * 16 + m];   // one row per lane now
        _Float16* st = &WT[0][0] + wave * 2176;   // 16 rows x 136 halves per wave

        #pragma unroll
        for (int nt = 0; nt < 8; nt++) {
            half4_t h;
            h[0] = (_Float16)(accs[nt][0] * ds);
            h[1] = (_Float16)(accs[nt][1] * ds);
            h[2] = (_Float16)(accs[nt][2] * ds);
            h[3] = (_Float16)(accs[nt][3] * ds);
            *(half4_t*)(st + m * 136 + nt * 16 + quad * 4) = h;
        }
        // Read back row-contiguous; every store instr = 16 rows x 64B full aligned lines.
        #pragma unroll
        for (int p = 0; p < 4; p++) {
            int r = lane & 15;
            int cc = (lane >> 4) + p * 4;       // 16B chunk index 0..15
            half8_t v = *(const half8_t*)(st + r * 136 + cc * 8);
            *(half8_t*)(out + (long)(tile * 16 + r) * 256 + cc * 8) = v;
        }
    }
}

// ---------------- K5: CSR gather aggregation + bias + ReLU (no atomics) ----------------
__launch_bounds__(256)
__global__ void k_agg(const _Float16* __restrict__ xwi1, const _Float16* __restrict__ xwi2,
                      const int* __restrict__ rp1, const int* __restrict__ col1,
                      const float* __restrict__ dinv1,
                      const int* __restrict__ rp2, const int* __restrict__ col2,
                      const float* __restrict__ dinv2,
                      const float* __restrict__ b1, const float* __restrict__ b2,
                      float* out) {
    int g = blockIdx.y;
    const _Float16* xwi = g ? xwi2 : xwi1;
    const int* rp = g ? rp2 : rp1;
    const int* col = g ? col2 : col1;
    const float* dinv = g ? dinv2 : dinv1;
    const float* bias = g ? b2 : b1;
    float* pos_out = out + (g ? 12800128L : 0L);
    float* neg_out = out + (g ? 19200128L : 6400000L);

    int t = threadIdx.x;
    int wave = t >> 6, lane = t & 63;
    int i = blockIdx.x * 4 + wave;
    if (i >= NN) return;
    int j4 = lane * 4;

    half4_t sv = *(const half4_t*)(xwi + (long)i * 256 + j4);
    float a0 = (float)sv[0], a1 = (float)sv[1], a2 = (float)sv[2], a3 = (float)sv[3];
    int e0 = rp[i], e1 = rp[i + 1];
    int e = e0;
    for (; e + 8 <= e1; e += 8) {
        int s0 = col[e + 0], s1 = col[e + 1], s2 = col[e + 2], s3 = col[e + 3];
        int s4 = col[e + 4], s5 = col[e + 5], s6 = col[e + 6], s7 = col[e + 7];
        half4_t v0 = *(const half4_t*)(xwi + (long)s0 * 256 + j4);
        half4_t v1 = *(const half4_t*)(xwi + (long)s1 * 256 + j4);
        half4_t v2 = *(const half4_t*)(xwi + (long)s2 * 256 + j4);
        half4_t v3 = *(const half4_t*)(xwi + (long)s3 * 256 + j4);
        half4_t v4 = *(const half4_t*)(xwi + (long)s4 * 256 + j4);
        half4_t v5 = *(const half4_t*)(xwi + (long)s5 * 256 + j4);
        half4_t v6 = *(const half4_t*)(xwi + (long)s6 * 256 + j4);
        half4_t v7 = *(const half4_t*)(xwi + (long)s7 * 256 + j4);
        a0 += (float)v0[0] + (float)v1[0] + (float)v2[0] + (float)v3[0]
            + (float)v4[0] + (float)v5[0] + (float)v6[0] + (float)v7[0];
        a1 += (float)v0[1] + (float)v1[1] + (float)v2[1] + (float)v3[1]
            + (float)v4[1] + (float)v5[1] + (float)v6[1] + (float)v7[1];
        a2 += (float)v0[2] + (float)v1[2] + (float)v2[2] + (float)v3[2]
            + (float)v4[2] + (float)v5[2] + (float)v6[2] + (float)v7[2];
        a3 += (float)v0[3] + (float)v1[3] + (float)v2[3] + (float)v3[3]
            + (float)v4[3] + (float)v5[3] + (float)v6[3] + (float)v7[3];
    }
    for (; e + 4 <= e1; e += 4) {
        int s0 = col[e + 0], s1 = col[e + 1], s2 = col[e + 2], s3 = col[e + 3];
        half4_t v0 = *(const half4_t*)(xwi + (long)s0 * 256 + j4);
        half4_t v1 = *(const half4_t*)(xwi + (long)s1 * 256 + j4);
        half4_t v2 = *(const half4_t*)(xwi + (long)s2 * 256 + j4);
        half4_t v3 = *(const half4_t*)(xwi + (long)s3 * 256 + j4);
        a0 += (float)v0[0] + (float)v1[0] + (float)v2[0] + (float)v3[0];
        a1 += (float)v0[1] + (float)v1[1] + (float)v2[1] + (float)v3[1];
        a2 += (float)v0[2] + (float)v1[2] + (float)v2[2] + (float)v3[2];
        a3 += (float)v0[3] + (float)v1[3] + (float)v2[3] + (float)v3[3];
    }
    for (; e < e1; e++) {
        int s = col[e];
        half4_t v = *(const half4_t*)(xwi + (long)s * 256 + j4);
        a0 += (float)v[0]; a1 += (float)v[1]; a2 += (float)v[2]; a3 += (float)v[3];
    }
    float di = dinv[i];
    int jj = (lane < 32) ? j4 : (j4 - 128);
    const f32x4* bp = (const f32x4*)(bias + jj);
    f32x4 bv = *bp;
    f32x4 o;
    o[0] = fmaxf(0.f, di * a0 + bv[0]);
    o[1] = fmaxf(0.f, di * a1 + bv[1]);
    o[2] = fmaxf(0.f, di * a2 + bv[2]);
    o[3] = fmaxf(0.f, di * a3 + bv[3]);
    float* dst = ((lane < 32) ? pos_out : neg_out) + (long)i * D + jj;
    __builtin_nontemporal_store(o, (f32x4*)dst);
}

// ---------------- K6: summary mean over pos_h ----------------
__launch_bounds__(256)
__global__ void k_sum(const float* __restrict__ pos1, const float* __restrict__ pos2,
                      float* s1, float* s2) {
    int g = blockIdx.y;
    const float* pos = g ? pos2 : pos1;
    float* s = g ? s2 : s1;
    int t = threadIdx.x;
    int rg = t >> 5;
    int j = (t & 31) * 4;
    float4 acc = {0.f, 0.f, 0.f, 0.f};
    for (int i = blockIdx.x * 8 + rg; i < NN; i += gridDim.x * 8) {
        float4 v = *(const float4*)(pos + (long)i * D + j);
        acc.x += v.x; acc.y += v.y; acc.z += v.z; acc.w += v.w;
    }
    __shared__ float sm[8][128];
    sm[rg][j + 0] = acc.x;
    sm[rg][j + 1] = acc.y;
    sm[rg][j + 2] = acc.z;
    sm[rg][j + 3] = acc.w;
    __syncthreads();
    if (t < 128) {
        float v = 0.f;
        for (int r = 0; r < 8; r++) v += sm[r][t];
        atomicAdd(&s[t], v * (1.0f / NN));
    }
}

extern "C" void kernel_launch(void* const* d_in, const int* in_sizes, int n_in,
                              void* d_out, int out_size, void* d_ws, size_t ws_size,
                              hipStream_t stream) {
    const float* x   = (const float*)d_in[0];
    const float* W1  = (const float*)d_in[1];
    const float* b1  = (const float*)d_in[2];
    const float* W2  = (const float*)d_in[3];
    const float* b2  = (const float*)d_in[4];
    const float* mp1 = (const float*)d_in[5];
    const float* mn1 = (const float*)d_in[6];
    const float* mp2 = (const float*)d_in[7];
    const float* mn2 = (const float*)d_in[8];
    const int* e1 = (const int*)d_in[9];
    const int* e2 = (const int*)d_in[10];
    const int* perm1 = (const int*)d_in[11];
    const int* perm2 = (const int*)d_in[12];
    const int* src1 = e1;       const int* dst1 = e1 + NE;
    const int* src2 = e2;       const int* dst2 = e2 + NE;
    float* out = (float*)d_out;

    // workspace carve
    char* w = (char*)d_ws;
    _Float16* xwi1 = (_Float16*)w; w += (size_t)NN * 256 * 2;  // 25.6 MB interleaved
    _Float16* xwi2 = (_Float16*)w; w += (size_t)NN * 256 * 2;
    int* cnt1 = (int*)w;  w += (size_t)NN * 4;
    int* cnt2 = (int*)w;  w += (size_t)NN * 4;
    int* cur1 = (int*)w;  w += (size_t)NN * 4;
    int* cur2 = (int*)w;  w += (size_t)NN * 4;
    int* rp1 = (int*)w;   w += (size_t)(NN + 4) * 4;
    int* rp2 = (int*)w;   w += (size_t)(NN + 4) * 4;
    int* col1 = (int*)w;  w += (size_t)NE * 4;
    int* col2 = (int*)w;  w += (size_t)NE * 4;
    float* dinv1 = (float*)w; w += (size_t)NN * 4;
    float* dinv2 = (float*)w; w += (size_t)NN * 4;
    int* part1 = (int*)w; w += (size_t)256 * 4;
    int* part2 = (int*)w; w += (size_t)256 * 4;

    float* s1 = out + 12800000L;
    float* s2 = out + 25600128L;
    const float* pos1 = out;
    const float* pos2 = out + 12800128L;

    k_init<<<dim3(256), 256, 0, stream>>>(cnt1, cnt2, s1, s2);
    k_count<<<dim3(1024), 256, 0, stream>>>(dst1, dst2, cnt1, cnt2);
    k_part<<<dim3(NB), 256, 0, stream>>>(cnt1, cnt2, part1, part2);
    k_scanp<<<dim3(1), 256, 0, stream>>>(part1, part2);
    k_apply<<<dim3(NB), 256, 0, stream>>>(cnt1, cnt2, part1, part2,
                                          rp1, rp2, cur1, cur2, dinv1, dinv2);
    k_fill_gemm<<<dim3(TOT_BLOCKS), 256, 0, stream>>>(
        src1, dst1, src2, dst2, cur1, cur2, col1, col2,
        x, W1, W2, mp1, mn1, mp2, mn2, perm1, perm2, dinv1, dinv2, xwi1, xwi2);
    k_agg<<<dim3(12500, 2), 256, 0, stream>>>(xwi1, xwi2,
                                              rp1, col1, dinv1, rp2, col2, dinv2,
                                              b1, b2, out);
    k_sum<<<dim3(128, 2), 256, 0, stream>>>(pos1, pos2, s1, s2);
}

// Round 2
// 521.115 us; speedup vs baseline: 1.2228x; 1.2228x over previous
//
#include <hip/hip_runtime.h>
#include <hip/hip_fp16.h>

#define NN 50000
#define NE 800000
#define D 128
#define NB 196        // ceil(50000/256)
#define FILL_BLOCKS 1024
#define GEMM_BLOCKS 3128   // 782 * 4
#define RNG 6250      // NN / 8 (dst range per XCD)
#define ESL 6250      // NE / 128 (edge slice per fill-rank)

typedef _Float16 half8_t __attribute__((ext_vector_type(8)));
typedef _Float16 half4_t __attribute__((ext_vector_type(4)));
typedef float f32x4 __attribute__((ext_vector_type(4)));

// ---------------- K0: init counters + summary slots ----------------
__global__ void k_init(int* cnt1, int* cnt2, float* s1, float* s2) {
    int i = blockIdx.x * blockDim.x + threadIdx.x;
    int stride = gridDim.x * blockDim.x;
    for (int j = i; j < NN; j += stride) { cnt1[j] = 0; cnt2[j] = 0; }
    if (i < D) { s1[i] = 0.f; s2[i] = 0.f; }
}

// ---------------- K1: in-degree histogram, XCD-binned ----------------
__global__ void k_count(const int* __restrict__ dst1, const int* __restrict__ dst2,
                        int* cnt1, int* cnt2) {
    int r = blockIdx.x & 7;
    int rank = blockIdx.x >> 3;          // 0..127
    unsigned lo = r * RNG;
    int base = rank * ESL;
    for (int e = base + threadIdx.x; e < base + ESL; e += 256) {
        int d1 = dst1[e];
        if ((unsigned)(d1 - lo) < RNG) atomicAdd(&cnt1[d1], 1);
        int d2 = dst2[e];
        if ((unsigned)(d2 - lo) < RNG) atomicAdd(&cnt2[d2], 1);
    }
}

// ---------------- K2a: per-block partial sums of counts (both graphs) ----------------
__global__ void k_part(const int* __restrict__ cnt1, const int* __restrict__ cnt2,
                       int* part1, int* part2) {
    __shared__ int sm1[256], sm2[256];
    int t = threadIdx.x;
    int idx = blockIdx.x * 256 + t;
    int v1 = (idx < NN) ? cnt1[idx] : 0;
    int v2 = (idx < NN) ? cnt2[idx] : 0;
    sm1[t] = v1; sm2[t] = v2;
    __syncthreads();
    for (int off = 128; off > 0; off >>= 1) {
        if (t < off) { sm1[t] += sm1[t + off]; sm2[t] += sm2[t + off]; }
        __syncthreads();
    }
    if (t == 0) { part1[blockIdx.x] = sm1[0]; part2[blockIdx.x] = sm2[0]; }
}

// ---------------- K2b: exclusive scan of block partials (one block) ----------------
__global__ void k_scanp(int* part1, int* part2) {
    __shared__ int sm1[256], sm2[256];
    int t = threadIdx.x;
    int v1 = (t < NB) ? part1[t] : 0;
    int v2 = (t < NB) ? part2[t] : 0;
    sm1[t] = v1; sm2[t] = v2;
    __syncthreads();
    for (int off = 1; off < 256; off <<= 1) {
        int a1 = (t >= off) ? sm1[t - off] : 0;
        int a2 = (t >= off) ? sm2[t - off] : 0;
        __syncthreads();
        sm1[t] += a1; sm2[t] += a2;
        __syncthreads();
    }
    if (t < NB) { part1[t] = sm1[t] - v1; part2[t] = sm2[t] - v2; }
}

// ---------------- K2c: apply block offsets -> rp, cur, dinv ----------------
__global__ void k_apply(const int* __restrict__ cnt1, const int* __restrict__ cnt2,
                        const int* __restrict__ part1, const int* __restrict__ part2,
                        int* rp1, int* rp2, int* cur1, int* cur2,
                        float* dinv1, float* dinv2) {
    __shared__ int sm1[256], sm2[256];
    int b = blockIdx.x, t = threadIdx.x;
    int idx = b * 256 + t;
    int v1 = (idx < NN) ? cnt1[idx] : 0;
    int v2 = (idx < NN) ? cnt2[idx] : 0;
    sm1[t] = v1; sm2[t] = v2;
    __syncthreads();
    for (int off = 1; off < 256; off <<= 1) {
        int a1 = (t >= off) ? sm1[t - off] : 0;
        int a2 = (t >= off) ? sm2[t - off] : 0;
        __syncthreads();
        sm1[t] += a1; sm2[t] += a2;
        __syncthreads();
    }
    int e1 = sm1[t] - v1 + part1[b];  // exclusive prefix
    int e2 = sm2[t] - v2 + part2[b];
    if (idx < NN) {
        rp1[idx] = e1; cur1[idx] = e1; dinv1[idx] = rsqrtf((float)(v1 + 1));
        rp2[idx] = e2; cur2[idx] = e2; dinv2[idx] = rsqrtf((float)(v2 + 1));
    } else if (idx == NN) {
        rp1[NN] = e1; rp2[NN] = e2;
    }
}

// ---------------- K3+K4 merged: fill-first (blocks 0..1023), then 4 GEMMs ----------------
// R1 post-mortem: interleaving fill with GEMM regressed 162->263us (occupancy 41->19%,
// L2 thrash on the fill's cur/col working set). Sequential fill-first restored.
// GEMM keeps the two verified R1 improvements:
//  - conflict-free W staging (SQ_LDS_BANK_CONFLICT 2.56e7 -> 2.2e6)
//  - swapped MFMA operands + LDS-transpose epilogue (full-line 64B stores)
__launch_bounds__(256)
__global__ void k_fill_gemm(const int* __restrict__ src1, const int* __restrict__ dst1,
                            const int* __restrict__ src2, const int* __restrict__ dst2,
                            int* cur1, int* cur2, int* col1, int* col2,
                            const float* __restrict__ x,
                            const float* __restrict__ W1, const float* __restrict__ W2,
                            const float* __restrict__ mp1, const float* __restrict__ mn1,
                            const float* __restrict__ mp2, const float* __restrict__ mn2,
                            const int* __restrict__ perm1, const int* __restrict__ perm2,
                            const float* __restrict__ dinv1, const float* __restrict__ dinv2,
                            _Float16* xwi1, _Float16* xwi2) {
    __shared__ __align__(16) _Float16 WT[128][136];   // 34816 B -> 4 blocks/CU
    int t = threadIdx.x;
    int bid = blockIdx.x;

    if (bid < FILL_BLOCKS) {
        // ---- FILL block: r = bid&7 selects dst range (XCD-local atomics) ----
        int r = bid & 7;
        int rank = bid >> 3;              // 0..127
        unsigned lo = r * RNG;
        int base = rank * ESL;
        for (int e = base + t; e < base + ESL; e += 256) {
            int d1 = dst1[e];
            if ((unsigned)(d1 - lo) < RNG) {
                int p = atomicAdd(&cur1[d1], 1);
                col1[p] = src1[e];
            }
            int d2 = dst2[e];
            if ((unsigned)(d2 - lo) < RNG) {
                int p = atomicAdd(&cur2[d2], 1);
                col2[p] = src2[e];
            }
        }
        return;
    }

    // ---- GEMM block ----
    int g = bid - FILL_BLOCKS;             // 0..3127
    int which = g / 782;                   // 0 = pos1, 1 = neg1, 2 = pos2, 3 = neg2
    int bx = g - which * 782;
    const float* W = (which < 2) ? W1 : W2;
    const float* mask = (which == 0) ? mp1 : (which == 1) ? mn1 : (which == 2) ? mp2 : mn2;
    const int* perm = (which == 1) ? perm1 : (which == 3) ? perm2 : nullptr;
    const float* dinv = (which < 2) ? dinv1 : dinv2;
    _Float16* out = ((which < 2) ? xwi1 : xwi2) + ((which & 1) ? 128 : 0);

    // W staging: column-chunk loads (coalesced) + half8 16B LDS writes (conflict-free).
    #pragma unroll
    for (int i = 0; i < 8; i++) {
        int idx = i * 256 + t;            // 0..2047
        int j = idx & 127;
        int k0 = (idx >> 7) * 8;          // 0,8,...,120
        half8_t h;
        #pragma unroll
        for (int c = 0; c < 8; c++) h[c] = (_Float16)W[(k0 + c) * 128 + j];
        *(half8_t*)(&WT[j][k0]) = h;      // WT[n][k], fp16
    }
    __syncthreads();

    int wave = t >> 6;
    int lane = t & 63;
    int quad = lane >> 4;
    int m = lane & 15;
    int tile = bx * 4 + wave;
    bool active = (tile * 16 < NN);       // no early return: barrier below

    f32x4 accs[8];
    if (active) {
        int row = tile * 16 + m;
        int grow = perm ? perm[row] : row;
        const float* xrow = x + (long)grow * D;
        const float* mrow = mask + (long)grow * D;

        half8_t a[4];
        #pragma unroll
        for (int kk = 0; kk < 4; kk++) {
            int k0 = kk * 32 + quad * 8;
            float4 xa = *(const float4*)(xrow + k0);
            float4 xb = *(const float4*)(xrow + k0 + 4);
            float4 ma = *(const float4*)(mrow + k0);
            float4 mb = *(const float4*)(mrow + k0 + 4);
            a[kk][0] = (_Float16)(xa.x * ma.x);
            a[kk][1] = (_Float16)(xa.y * ma.y);
            a[kk][2] = (_Float16)(xa.z * ma.z);
            a[kk][3] = (_Float16)(xa.w * ma.w);
            a[kk][4] = (_Float16)(xb.x * mb.x);
            a[kk][5] = (_Float16)(xb.y * mb.y);
            a[kk][6] = (_Float16)(xb.z * mb.z);
            a[kk][7] = (_Float16)(xb.w * mb.w);
        }

        // Swapped operands: A = W-fragment (i = out-col), B = x-fragment (j = x-row).
        #pragma unroll
        for (int nt = 0; nt < 8; nt++) {
            f32x4 acc = {0.f, 0.f, 0.f, 0.f};
            #pragma unroll
            for (int kk = 0; kk < 4; kk++) {
                half8_t w = *(const half8_t*)(&WT[nt * 16 + m][kk * 32 + quad * 8]);
                acc = __builtin_amdgcn_mfma_f32_16x16x32_f16(w, a[kk], acc, 0, 0, 0);
            }
            accs[nt] = acc;
        }
    }

    // All waves done reading WT -> reuse it as per-wave transpose staging.
    __syncthreads();

    if (active) {
        float ds = dinv[tile * 16 + m];   // one row per lane
        _Float16* st = &WT[0][0] + wave * 2176;   // 16 rows x 136 halves per wave

        #pragma unroll
        for (int nt = 0; nt < 8; nt++) {
            half4_t h;
            h[0] = (_Float16)(accs[nt][0] * ds);
            h[1] = (_Float16)(accs[nt][1] * ds);
            h[2] = (_Float16)(accs[nt][2] * ds);
            h[3] = (_Float16)(accs[nt][3] * ds);
            *(half4_t*)(st + m * 136 + nt * 16 + quad * 4) = h;
        }
        // Read back row-contiguous; every store instr = 16 rows x 64B full aligned lines.
        #pragma unroll
        for (int p = 0; p < 4; p++) {
            int r = lane & 15;
            int cc = (lane >> 4) + p * 4;       // 16B chunk index 0..15
            half8_t v = *(const half8_t*)(st + r * 136 + cc * 8);
            *(half8_t*)(out + (long)(tile * 16 + r) * 256 + cc * 8) = v;
        }
    }
}

// ---------------- K5: CSR gather aggregation + bias + ReLU (no atomics) ----------------
__launch_bounds__(256)
__global__ void k_agg(const _Float16* __restrict__ xwi1, const _Float16* __restrict__ xwi2,
                      const int* __restrict__ rp1, const int* __restrict__ col1,
                      const float* __restrict__ dinv1,
                      const int* __restrict__ rp2, const int* __restrict__ col2,
                      const float* __restrict__ dinv2,
                      const float* __restrict__ b1, const float* __restrict__ b2,
                      float* out) {
    int g = blockIdx.y;
    const _Float16* xwi = g ? xwi2 : xwi1;
    const int* rp = g ? rp2 : rp1;
    const int* col = g ? col2 : col1;
    const float* dinv = g ? dinv2 : dinv1;
    const float* bias = g ? b2 : b1;
    float* pos_out = out + (g ? 12800128L : 0L);
    float* neg_out = out + (g ? 19200128L : 6400000L);

    int t = threadIdx.x;
    int wave = t >> 6, lane = t & 63;
    int i = blockIdx.x * 4 + wave;
    if (i >= NN) return;
    int j4 = lane * 4;

    half4_t sv = *(const half4_t*)(xwi + (long)i * 256 + j4);
    float a0 = (float)sv[0], a1 = (float)sv[1], a2 = (float)sv[2], a3 = (float)sv[3];
    int e0 = rp[i], e1 = rp[i + 1];
    int e = e0;
    for (; e + 8 <= e1; e += 8) {
        int s0 = col[e + 0], s1 = col[e + 1], s2 = col[e + 2], s3 = col[e + 3];
        int s4 = col[e + 4], s5 = col[e + 5], s6 = col[e + 6], s7 = col[e + 7];
        half4_t v0 = *(const half4_t*)(xwi + (long)s0 * 256 + j4);
        half4_t v1 = *(const half4_t*)(xwi + (long)s1 * 256 + j4);
        half4_t v2 = *(const half4_t*)(xwi + (long)s2 * 256 + j4);
        half4_t v3 = *(const half4_t*)(xwi + (long)s3 * 256 + j4);
        half4_t v4 = *(const half4_t*)(xwi + (long)s4 * 256 + j4);
        half4_t v5 = *(const half4_t*)(xwi + (long)s5 * 256 + j4);
        half4_t v6 = *(const half4_t*)(xwi + (long)s6 * 256 + j4);
        half4_t v7 = *(const half4_t*)(xwi + (long)s7 * 256 + j4);
        a0 += (float)v0[0] + (float)v1[0] + (float)v2[0] + (float)v3[0]
            + (float)v4[0] + (float)v5[0] + (float)v6[0] + (float)v7[0];
        a1 += (float)v0[1] + (float)v1[1] + (float)v2[1] + (float)v3[1]
            + (float)v4[1] + (float)v5[1] + (float)v6[1] + (float)v7[1];
        a2 += (float)v0[2] + (float)v1[2] + (float)v2[2] + (float)v3[2]
            + (float)v4[2] + (float)v5[2] + (float)v6[2] + (float)v7[2];
        a3 += (float)v0[3] + (float)v1[3] + (float)v2[3] + (float)v3[3]
            + (float)v4[3] + (float)v5[3] + (float)v6[3] + (float)v7[3];
    }
    for (; e + 4 <= e1; e += 4) {
        int s0 = col[e + 0], s1 = col[e + 1], s2 = col[e + 2], s3 = col[e + 3];
        half4_t v0 = *(const half4_t*)(xwi + (long)s0 * 256 + j4);
        half4_t v1 = *(const half4_t*)(xwi + (long)s1 * 256 + j4);
        half4_t v2 = *(const half4_t*)(xwi + (long)s2 * 256 + j4);
        half4_t v3 = *(const half4_t*)(xwi + (long)s3 * 256 + j4);
        a0 += (float)v0[0] + (float)v1[0] + (float)v2[0] + (float)v3[0];
        a1 += (float)v0[1] + (float)v1[1] + (float)v2[1] + (float)v3[1];
        a2 += (float)v0[2] + (float)v1[2] + (float)v2[2] + (float)v3[2];
        a3 += (float)v0[3] + (float)v1[3] + (float)v2[3] + (float)v3[3];
    }
    for (; e < e1; e++) {
        int s = col[e];
        half4_t v = *(const half4_t*)(xwi + (long)s * 256 + j4);
        a0 += (float)v[0]; a1 += (float)v[1]; a2 += (float)v[2]; a3 += (float)v[3];
    }
    float di = dinv[i];
    int jj = (lane < 32) ? j4 : (j4 - 128);
    const f32x4* bp = (const f32x4*)(bias + jj);
    f32x4 bv = *bp;
    f32x4 o;
    o[0] = fmaxf(0.f, di * a0 + bv[0]);
    o[1] = fmaxf(0.f, di * a1 + bv[1]);
    o[2] = fmaxf(0.f, di * a2 + bv[2]);
    o[3] = fmaxf(0.f, di * a3 + bv[3]);
    float* dst = ((lane < 32) ? pos_out : neg_out) + (long)i * D + jj;
    __builtin_nontemporal_store(o, (f32x4*)dst);
}

// ---------------- K6: summary mean over pos_h ----------------
__launch_bounds__(256)
__global__ void k_sum(const float* __restrict__ pos1, const float* __restrict__ pos2,
                      float* s1, float* s2) {
    int g = blockIdx.y;
    const float* pos = g ? pos2 : pos1;
    float* s = g ? s2 : s1;
    int t = threadIdx.x;
    int rg = t >> 5;
    int j = (t & 31) * 4;
    float4 acc = {0.f, 0.f, 0.f, 0.f};
    for (int i = blockIdx.x * 8 + rg; i < NN; i += gridDim.x * 8) {
        float4 v = *(const float4*)(pos + (long)i * D + j);
        acc.x += v.x; acc.y += v.y; acc.z += v.z; acc.w += v.w;
    }
    __shared__ float sm[8][128];
    sm[rg][j + 0] = acc.x;
    sm[rg][j + 1] = acc.y;
    sm[rg][j + 2] = acc.z;
    sm[rg][j + 3] = acc.w;
    __syncthreads();
    if (t < 128) {
        float v = 0.f;
        for (int r = 0; r < 8; r++) v += sm[r][t];
        atomicAdd(&s[t], v * (1.0f / NN));
    }
}

extern "C" void kernel_launch(void* const* d_in, const int* in_sizes, int n_in,
                              void* d_out, int out_size, void* d_ws, size_t ws_size,
                              hipStream_t stream) {
    const float* x   = (const float*)d_in[0];
    const float* W1  = (const float*)d_in[1];
    const float* b1  = (const float*)d_in[2];
    const float* W2  = (const float*)d_in[3];
    const float* b2  = (const float*)d_in[4];
    const float* mp1 = (const float*)d_in[5];
    const float* mn1 = (const float*)d_in[6];
    const float* mp2 = (const float*)d_in[7];
    const float* mn2 = (const float*)d_in[8];
    const int* e1 = (const int*)d_in[9];
    const int* e2 = (const int*)d_in[10];
    const int* perm1 = (const int*)d_in[11];
    const int* perm2 = (const int*)d_in[12];
    const int* src1 = e1;       const int* dst1 = e1 + NE;
    const int* src2 = e2;       const int* dst2 = e2 + NE;
    float* out = (float*)d_out;

    // workspace carve
    char* w = (char*)d_ws;
    _Float16* xwi1 = (_Float16*)w; w += (size_t)NN * 256 * 2;  // 25.6 MB interleaved
    _Float16* xwi2 = (_Float16*)w; w += (size_t)NN * 256 * 2;
    int* cnt1 = (int*)w;  w += (size_t)NN * 4;
    int* cnt2 = (int*)w;  w += (size_t)NN * 4;
    int* cur1 = (int*)w;  w += (size_t)NN * 4;
    int* cur2 = (int*)w;  w += (size_t)NN * 4;
    int* rp1 = (int*)w;   w += (size_t)(NN + 4) * 4;
    int* rp2 = (int*)w;   w += (size_t)(NN + 4) * 4;
    int* col1 = (int*)w;  w += (size_t)NE * 4;
    int* col2 = (int*)w;  w += (size_t)NE * 4;
    float* dinv1 = (float*)w; w += (size_t)NN * 4;
    float* dinv2 = (float*)w; w += (size_t)NN * 4;
    int* part1 = (int*)w; w += (size_t)256 * 4;
    int* part2 = (int*)w; w += (size_t)256 * 4;

    float* s1 = out + 12800000L;
    float* s2 = out + 25600128L;
    const float* pos1 = out;
    const float* pos2 = out + 12800128L;

    k_init<<<dim3(256), 256, 0, stream>>>(cnt1, cnt2, s1, s2);
    k_count<<<dim3(1024), 256, 0, stream>>>(dst1, dst2, cnt1, cnt2);
    k_part<<<dim3(NB), 256, 0, stream>>>(cnt1, cnt2, part1, part2);
    k_scanp<<<dim3(1), 256, 0, stream>>>(part1, part2);
    k_apply<<<dim3(NB), 256, 0, stream>>>(cnt1, cnt2, part1, part2,
                                          rp1, rp2, cur1, cur2, dinv1, dinv2);
    k_fill_gemm<<<dim3(FILL_BLOCKS + GEMM_BLOCKS), 256, 0, stream>>>(
        src1, dst1, src2, dst2, cur1, cur2, col1, col2,
        x, W1, W2, mp1, mn1, mp2, mn2, perm1, perm2, dinv1, dinv2, xwi1, xwi2);
    k_agg<<<dim3(12500, 2), 256, 0, stream>>>(xwi1, xwi2,
                                              rp1, col1, dinv1, rp2, col2, dinv2,
                                              b1, b2, out);
    k_sum<<<dim3(128, 2), 256, 0, stream>>>(pos1, pos2, s1, s2);
}